// Round 7
// baseline (196.837 us; speedup 1.0000x reference)
//
#include <hip/hip_runtime.h>
#include <cmath>

#define B_    4
#define S_    512
#define NH_   8
#define TOT_  104
#define NQKV_ 832
#define ROWS_ 2048

typedef float f32x4 __attribute__((ext_vector_type(4)));
typedef short short8 __attribute__((ext_vector_type(8)));

__device__ inline float bfu2f(unsigned int bits16) {
  union { unsigned int i; float f; } v; v.i = bits16 << 16; return v.f;
}
__device__ inline unsigned short f2bf(float f) {
  union { float f; unsigned int i; } v; v.f = f;
  unsigned int r = v.i + 0x7fffu + ((v.i >> 16) & 1u);
  return (unsigned short)(r >> 16);
}
__device__ inline short8 ld8(const unsigned short* p) {
  union { uint4 u; short8 s; } v; v.u = *(const uint4*)p; return v.s;
}
// pack 8 f32 (two float4) -> short8 bf16
__device__ inline short8 pk8(float4 a, float4 b) {
  union { unsigned short us[8]; short8 s; } v;
  v.us[0]=f2bf(a.x); v.us[1]=f2bf(a.y); v.us[2]=f2bf(a.z); v.us[3]=f2bf(a.w);
  v.us[4]=f2bf(b.x); v.us[5]=f2bf(b.y); v.us[6]=f2bf(b.z); v.us[7]=f2bf(b.w);
  return v.s;
}

// ---------------------------------------------------------------------------
// K1: MFMA QKV projection from f32 inputs (inline bf16 cast).
// C[2048,832] = H @ Wqkv^T. Epilogue scatters to Qnb/Knb [bh][i][32] bf16,
// Vtb [bh][v][512] bf16 (transposed), Qr f32.
// ---------------------------------------------------------------------------
__global__ __launch_bounds__(256) void k1_qkv(const float* __restrict__ Hin,
                                              const float* __restrict__ Wqkv,
                                              unsigned short* __restrict__ Qnb,
                                              unsigned short* __restrict__ Knb,
                                              unsigned short* __restrict__ Vtb,
                                              float* __restrict__ Qr) {
  const int t = threadIdx.x;
  const int w = t >> 6, l = t & 63;
  const int lm = l & 15, lk = (l >> 4) << 3;
  const int i0 = blockIdx.y * 64 + w * 16;
  const int n0 = blockIdx.x * 64;
  f32x4 acc[4] = {};
  for (int k0 = 0; k0 < 256; k0 += 32) {
    const float* ap = Hin + (size_t)(i0 + lm) * 256 + k0 + lk;
    short8 a = pk8(*(const float4*)ap, *(const float4*)(ap + 4));
#pragma unroll
    for (int nf = 0; nf < 4; ++nf) {
      const float* bp = Wqkv + (size_t)(n0 + nf * 16 + lm) * 256 + k0 + lk;
      short8 b = pk8(*(const float4*)bp, *(const float4*)(bp + 4));
      acc[nf] = __builtin_amdgcn_mfma_f32_16x16x32_bf16(a, b, acc[nf], 0, 0, 0);
    }
  }
  const int rbase = i0 + ((l >> 4) << 2);
#pragma unroll
  for (int nf = 0; nf < 4; ++nf) {
#pragma unroll
    for (int r = 0; r < 4; ++r) {
      int row = rbase + r;
      int c = n0 + nf * 16 + lm;
      int b_ = row >> 9, i = row & 511;
      int h = c / 104, o = c - h * 104;
      float v = acc[nf][r];
      size_t bh = (size_t)(b_ * 8 + h);
      if (o < 32)       Qnb[(bh * 512 + i) * 32 + o] = f2bf(v);
      else if (o < 64)  Knb[(bh * 512 + i) * 32 + (o - 32)] = f2bf(v);
      else if (o < 96)  Vtb[(bh * 32 + (o - 64)) * 512 + i] = f2bf(v);
      else              Qr[(size_t)row * 64 + h * 8 + (o - 96)] = v;
    }
  }
}

// ---------------------------------------------------------------------------
// K1c: qrr[row][h*16+r] = sum_k Qr[row][h*8+k] * Wd[(h*8+k)*16+r]
// ---------------------------------------------------------------------------
__global__ __launch_bounds__(256) void k1c_qrr(const float* __restrict__ Qr,
                                               const float* __restrict__ Wd,
                                               float* __restrict__ qrrg) {
  int t = threadIdx.x;
  int row = blockIdx.x * 2 + (t >> 7);
  int c = t & 127, h = c >> 4, r = c & 15;
  float s = 0.f;
#pragma unroll
  for (int k = 0; k < 8; ++k)
    s += Qr[(size_t)row * 64 + h * 8 + k] * Wd[(h * 8 + k) * 16 + r];
  qrrg[(size_t)row * 128 + c] = s;
}

// ---------------------------------------------------------------------------
// K2: MFMA QK^T per (b,h): sqk[bh][i][j] bf16 = Qn[512,32] @ Kn[512,32]^T
// ---------------------------------------------------------------------------
__global__ __launch_bounds__(256) void k2_qk(const unsigned short* __restrict__ Qnb,
                                             const unsigned short* __restrict__ Knb,
                                             unsigned short* __restrict__ sqk) {
  const int t = threadIdx.x;
  const int w = t >> 6, l = t & 63;
  const int lm = l & 15, lk = (l >> 4) << 3;
  const int bh = blockIdx.z;
  const int i0 = blockIdx.y * 64 + w * 16, j0 = blockIdx.x * 64;
  short8 a = ld8(Qnb + ((size_t)bh * 512 + i0 + lm) * 32 + lk);
  f32x4 acc[4] = {};
#pragma unroll
  for (int nf = 0; nf < 4; ++nf) {
    short8 b = ld8(Knb + ((size_t)bh * 512 + j0 + nf * 16 + lm) * 32 + lk);
    acc[nf] = __builtin_amdgcn_mfma_f32_16x16x32_bf16(a, b, acc[nf], 0, 0, 0);
  }
  const int rbase = i0 + ((l >> 4) << 2);
#pragma unroll
  for (int nf = 0; nf < 4; ++nf)
#pragma unroll
    for (int r = 0; r < 4; ++r)
      sqk[((size_t)bh * 512 + rbase + r) * 512 + j0 + nf * 16 + lm] = f2bf(acc[nf][r]);
}

// ---------------------------------------------------------------------------
// K3: per (b,i): scores = scale*(sqk + qrr.rd) + mask ; softmax ;
//     probs bf16 -> global ; pr = p.rd ; route-ctx -> ctx
// Route row kept in LDS as packed bf16 pairs (20KB) -> 5 blocks/CU.
// ---------------------------------------------------------------------------
__global__ __launch_bounds__(256) void k3_route(const float* __restrict__ rd,
                                                const unsigned short* __restrict__ sqk,
                                                const float* __restrict__ qrrg,
                                                const float* __restrict__ Wroute,
                                                const float* __restrict__ mask,
                                                unsigned short* __restrict__ probs,
                                                float* __restrict__ ctx) {
  __shared__ unsigned int rdp[512][10];    // 8 used + 2 pad (b64-friendly, <=2-way banks)
  __shared__ unsigned int sc_bf[8][257];   // packed (j, j+256) bf16 pairs
  __shared__ float qrr[8][16];
  __shared__ float prp[4][64][2];
  __shared__ float prf[8][16];
  const int t = threadIdx.x;
  const int row = blockIdx.x, b = row >> 9, i = row & 511;

  // stage rd row (512 x 16 f32) as packed bf16 pairs
  const float4* rp = (const float4*)(rd + (size_t)row * 8192);
#pragma unroll
  for (int q = 0; q < 8; ++q) {
    int idx = q * 256 + t;
    float4 v = rp[idx];
    int j = idx >> 2, u0 = (idx & 3) * 2;
    rdp[j][u0]     = (unsigned int)f2bf(v.x) | ((unsigned int)f2bf(v.y) << 16);
    rdp[j][u0 + 1] = (unsigned int)f2bf(v.z) | ((unsigned int)f2bf(v.w) << 16);
  }
  if (t < 128) ((float*)qrr)[t] = qrrg[(size_t)row * 128 + t];
  __syncthreads();

  // pass A: thread owns j = t (lo) and j+256 (hi)
  const float scal = 0.15811388300841898f;
  {
    float rlo[16], rhi[16];
#pragma unroll
    for (int q = 0; q < 4; ++q) {
      uint2 ua = *(const uint2*)&rdp[t][q * 2];
      uint2 uc = *(const uint2*)&rdp[t + 256][q * 2];
      rlo[q*4]   = bfu2f(ua.x & 0xffffu); rlo[q*4+1] = bfu2f(ua.x >> 16);
      rlo[q*4+2] = bfu2f(ua.y & 0xffffu); rlo[q*4+3] = bfu2f(ua.y >> 16);
      rhi[q*4]   = bfu2f(uc.x & 0xffffu); rhi[q*4+1] = bfu2f(uc.x >> 16);
      rhi[q*4+2] = bfu2f(uc.y & 0xffffu); rhi[q*4+3] = bfu2f(uc.y >> 16);
    }
    float mlo = mask[b * 512 + t], mhi = mask[b * 512 + t + 256];
#pragma unroll
    for (int h = 0; h < 8; ++h) {
      float slo = 0.f, shi = 0.f;
#pragma unroll
      for (int r = 0; r < 16; ++r) { slo += qrr[h][r] * rlo[r]; shi += qrr[h][r] * rhi[r]; }
      const unsigned short* qp = sqk + ((size_t)(b * 8 + h) * 512 + i) * 512;
      float qlo = bfu2f(qp[t]), qhi = bfu2f(qp[t + 256]);
      float vlo = scal * (qlo + slo) + mlo;
      float vhi = scal * (qhi + shi) + mhi;
      sc_bf[h][t] = (unsigned int)f2bf(vlo) | ((unsigned int)f2bf(vhi) << 16);
    }
  }
  __syncthreads();

  // softmax: wave handles 2 heads; lane covers jj = lane + 64*cq, both halves
  const int wave = t >> 6, lane = t & 63;
  for (int hh = 0; hh < 2; ++hh) {
    int h = wave * 2 + hh;
    float vlo[4], vhi[4];
    float m = -1e30f;
#pragma unroll
    for (int cq = 0; cq < 4; ++cq) {
      unsigned int u = sc_bf[h][lane + 64 * cq];
      vlo[cq] = bfu2f(u & 0xffffu); vhi[cq] = bfu2f(u >> 16);
      m = fmaxf(m, fmaxf(vlo[cq], vhi[cq]));
    }
#pragma unroll
    for (int o = 32; o; o >>= 1) m = fmaxf(m, __shfl_xor(m, o));
    float ssum = 0.f;
#pragma unroll
    for (int cq = 0; cq < 4; ++cq) {
      vlo[cq] = __expf(vlo[cq] - m); vhi[cq] = __expf(vhi[cq] - m);
      ssum += vlo[cq] + vhi[cq];
    }
#pragma unroll
    for (int o = 32; o; o >>= 1) ssum += __shfl_xor(ssum, o);
    float inv = 1.0f / ssum;
    unsigned short* pout = probs + ((size_t)(b * 8 + h) * 512 + i) * 512;
#pragma unroll
    for (int cq = 0; cq < 4; ++cq) {
      int jj = lane + 64 * cq;
      unsigned short plo = f2bf(vlo[cq] * inv), phi = f2bf(vhi[cq] * inv);
      pout[jj] = plo; pout[jj + 256] = phi;
      sc_bf[h][jj] = (unsigned int)plo | ((unsigned int)phi << 16);
    }
  }
  __syncthreads();

  // pass B: pr[h][r] = sum_j p[h][j]*rd[j][r]
  {
    int c = t & 63, qj = t >> 6;
    int h = c >> 3, ru = c & 7;
    float p0 = 0.f, p1 = 0.f;
    for (int jj = qj * 64; jj < qj * 64 + 64; ++jj) {
      unsigned int u = sc_bf[h][jj];
      unsigned int rr = rdp[jj][ru];
      unsigned int r2 = rdp[jj + 256][ru];
      float plo = bfu2f(u & 0xffffu), phi = bfu2f(u >> 16);
      p0 += plo * bfu2f(rr & 0xffffu) + phi * bfu2f(r2 & 0xffffu);
      p1 += plo * bfu2f(rr >> 16)     + phi * bfu2f(r2 >> 16);
    }
    prp[qj][c][0] = p0; prp[qj][c][1] = p1;
  }
  __syncthreads();
  if (t < 128) {
    int h = t >> 4, r = t & 15;
    int c = h * 8 + (r >> 1), part = r & 1;
    prf[h][r] = prp[0][c][part] + prp[1][c][part] + prp[2][c][part] + prp[3][c][part];
  }
  __syncthreads();

  // route context
  {
    int h = t >> 5;
    float s = 0.f;
#pragma unroll
    for (int r = 0; r < 16; ++r) s += prf[h][r] * Wroute[t * 16 + r];
    ctx[(size_t)row * 256 + t] = s;
  }
}

// ---------------------------------------------------------------------------
// K4: MFMA PV per (b,h, i-tile 64, j-quarter): ctx += P @ V  (atomic)
// ---------------------------------------------------------------------------
__global__ __launch_bounds__(256) void k4_pv(const unsigned short* __restrict__ probs,
                                             const unsigned short* __restrict__ Vtb,
                                             float* __restrict__ ctx) {
  const int t = threadIdx.x;
  const int w = t >> 6, l = t & 63;
  const int lm = l & 15, lk = (l >> 4) << 3;
  const int bh = blockIdx.y;
  const int b = bh >> 3, h = bh & 7;
  const int irow = blockIdx.x * 64 + w * 16 + lm;
  const int kbase = blockIdx.z * 128;
  f32x4 acc[2] = {};
  for (int k0 = kbase; k0 < kbase + 128; k0 += 32) {
    short8 a = ld8(probs + ((size_t)bh * 512 + irow) * 512 + k0 + lk);
#pragma unroll
    for (int nf = 0; nf < 2; ++nf) {
      short8 bb = ld8(Vtb + ((size_t)bh * 32 + nf * 16 + lm) * 512 + k0 + lk);
      acc[nf] = __builtin_amdgcn_mfma_f32_16x16x32_bf16(a, bb, acc[nf], 0, 0, 0);
    }
  }
  const int rbase = blockIdx.x * 64 + w * 16 + ((l >> 4) << 2);
#pragma unroll
  for (int nf = 0; nf < 2; ++nf)
#pragma unroll
    for (int r = 0; r < 4; ++r) {
      size_t addr = ((size_t)b * 512 + rbase + r) * 256 + h * 32 + nf * 16 + lm;
      atomicAdd(&ctx[addr], acc[nf][r]);
    }
}

// ---------------------------------------------------------------------------
// K5: out = LN(ctx @ W_out.T + b_out) + H   (4 rows/block, f32)
// ---------------------------------------------------------------------------
__global__ __launch_bounds__(256) void k5_out(const float* __restrict__ ctx,
                                              const float* __restrict__ Wout,
                                              const float* __restrict__ bout,
                                              const float* __restrict__ lnw,
                                              const float* __restrict__ lnb,
                                              const float* __restrict__ Hin,
                                              float* __restrict__ out) {
  __shared__ float buf[4][257];
  __shared__ float uarr[4], rarr[4];
  const int t = threadIdx.x;
  const int R0 = blockIdx.x * 4;
  {
    int sr = t >> 6, c0 = (t & 63) * 4;
    float4 a = *(const float4*)(ctx + (size_t)(R0 + sr) * 256 + c0);
    buf[sr][c0+0]=a.x; buf[sr][c0+1]=a.y; buf[sr][c0+2]=a.z; buf[sr][c0+3]=a.w;
  }
  __syncthreads();

  float o[4];
  {
    float bo = bout[t];
#pragma unroll
    for (int r = 0; r < 4; ++r) o[r] = bo;
  }
  const float4* wp = (const float4*)(Wout + (size_t)t * 256);
  for (int d4 = 0; d4 < 64; ++d4) {
    float4 w = wp[d4];
    int d = d4 * 4;
#pragma unroll
    for (int r = 0; r < 4; ++r)
      o[r] += buf[r][d]*w.x + buf[r][d+1]*w.y + buf[r][d+2]*w.z + buf[r][d+3]*w.w;
  }
  __syncthreads();
#pragma unroll
  for (int r = 0; r < 4; ++r) buf[r][t] = o[r];
  __syncthreads();
  {
    int wave = t >> 6, lane = t & 63;
    int r = wave;
    float s = 0.f, sq = 0.f;
#pragma unroll
    for (int c = 0; c < 4; ++c) {
      float x = buf[r][lane + 64*c];
      s += x; sq += x*x;
    }
#pragma unroll
    for (int off = 32; off; off >>= 1) {
      s += __shfl_xor(s, off);
      sq += __shfl_xor(sq, off);
    }
    if (lane == 0) {
      float u = s * (1.0f/256.0f);
      uarr[r] = u;
      rarr[r] = rsqrtf(sq * (1.0f/256.0f) - u*u + 1e-12f);
    }
  }
  __syncthreads();
  {
    float lw = lnw[t], lb = lnb[t];
#pragma unroll
    for (int r = 0; r < 4; ++r) {
      size_t R = R0 + r;
      out[R * 256 + t] = lw * (o[r] - uarr[r]) * rarr[r] + lb + Hin[R * 256 + t];
    }
  }
}

// ---------------------------------------------------------------------------
extern "C" void kernel_launch(void* const* d_in, const int* in_sizes, int n_in,
                              void* d_out, int out_size, void* d_ws, size_t ws_size,
                              hipStream_t stream) {
  const float* Hin    = (const float*)d_in[0];
  const float* rd     = (const float*)d_in[1];
  const float* mask   = (const float*)d_in[2];
  const float* Wqkv   = (const float*)d_in[3];
  const float* Wd     = (const float*)d_in[4];
  const float* Wroute = (const float*)d_in[5];
  const float* Wout   = (const float*)d_in[6];
  const float* bout   = (const float*)d_in[7];
  const float* lnw    = (const float*)d_in[8];
  const float* lnb    = (const float*)d_in[9];
  float* out = (float*)d_out;

  unsigned short* Qnb   = (unsigned short*)d_ws;       // 524,288
  unsigned short* Knb   = Qnb + 524288;                // 524,288
  unsigned short* Vtb   = Knb + 524288;                // 524,288
  unsigned short* sqk   = Vtb + 524288;                // 8,388,608
  unsigned short* probs = sqk + 8388608;               // 8,388,608
  float* Qr   = (float*)(probs + 8388608);             // 131,072 f
  float* qrrg = Qr + 131072;                           // 262,144 f
  float* ctx  = qrrg + 262144;                         // 524,288 f

  k1_qkv  <<<dim3(13, 32),      256, 0, stream>>>(Hin, Wqkv, Qnb, Knb, Vtb, Qr);
  k1c_qrr <<<1024,              256, 0, stream>>>(Qr, Wd, qrrg);
  k2_qk   <<<dim3(8, 8, 32),    256, 0, stream>>>(Qnb, Knb, sqk);
  k3_route<<<2048,              256, 0, stream>>>(rd, sqk, qrrg, Wroute, mask, probs, ctx);
  k4_pv   <<<dim3(8, 32, 4),    256, 0, stream>>>(probs, Vtb, ctx);
  k5_out  <<<512,               256, 0, stream>>>(ctx, Wout, bout, lnw, lnb, Hin, out);
}

// Round 8
// 196.061 us; speedup vs baseline: 1.0040x; 1.0040x over previous
//
#include <hip/hip_runtime.h>
#include <cmath>

#define B_    4
#define S_    512
#define NH_   8
#define TOT_  104
#define NQKV_ 832
#define ROWS_ 2048

typedef float f32x4 __attribute__((ext_vector_type(4)));
typedef short short8 __attribute__((ext_vector_type(8)));

__device__ inline float bfu2f(unsigned int bits16) {
  union { unsigned int i; float f; } v; v.i = bits16 << 16; return v.f;
}
__device__ inline unsigned short f2bf(float f) {
  union { float f; unsigned int i; } v; v.f = f;
  unsigned int r = v.i + 0x7fffu + ((v.i >> 16) & 1u);
  return (unsigned short)(r >> 16);
}
__device__ inline unsigned int pk2(float a, float b) {
  return (unsigned int)f2bf(a) | ((unsigned int)f2bf(b) << 16);
}
__device__ inline short8 ld8(const unsigned short* p) {
  union { uint4 u; short8 s; } v; v.u = *(const uint4*)p; return v.s;
}
// pack 8 f32 (two float4) -> short8 bf16
__device__ inline short8 pk8(float4 a, float4 b) {
  union { unsigned short us[8]; short8 s; } v;
  v.us[0]=f2bf(a.x); v.us[1]=f2bf(a.y); v.us[2]=f2bf(a.z); v.us[3]=f2bf(a.w);
  v.us[4]=f2bf(b.x); v.us[5]=f2bf(b.y); v.us[6]=f2bf(b.z); v.us[7]=f2bf(b.w);
  return v.s;
}

// ---------------------------------------------------------------------------
// K0: Wco[d][h*16+r] = sum_v Wout[d][h*32+v] * Wroute[(h*32+v)][r]
// (folds route-context through the output projection)
// ---------------------------------------------------------------------------
__global__ __launch_bounds__(256) void k0_wco(const float* __restrict__ Wout,
                                              const float* __restrict__ Wroute,
                                              float* __restrict__ Wco) {
  const int t = threadIdx.x;
  const int d = blockIdx.x * 2 + (t >> 7);
  const int c = t & 127, h = c >> 4, r = c & 15;
  float s = 0.f;
#pragma unroll
  for (int v = 0; v < 32; ++v)
    s += Wout[(size_t)d * 256 + h * 32 + v] * Wroute[(h * 32 + v) * 16 + r];
  Wco[(size_t)d * 128 + c] = s;
}

// ---------------------------------------------------------------------------
// K1: MFMA QKV projection from f32 inputs (inline bf16 cast).
// ---------------------------------------------------------------------------
__global__ __launch_bounds__(256) void k1_qkv(const float* __restrict__ Hin,
                                              const float* __restrict__ Wqkv,
                                              unsigned short* __restrict__ Qnb,
                                              unsigned short* __restrict__ Knb,
                                              unsigned short* __restrict__ Vtb,
                                              float* __restrict__ Qr) {
  const int t = threadIdx.x;
  const int w = t >> 6, l = t & 63;
  const int lm = l & 15, lk = (l >> 4) << 3;
  const int i0 = blockIdx.y * 64 + w * 16;
  const int n0 = blockIdx.x * 64;
  f32x4 acc[4] = {};
  for (int k0 = 0; k0 < 256; k0 += 32) {
    const float* ap = Hin + (size_t)(i0 + lm) * 256 + k0 + lk;
    short8 a = pk8(*(const float4*)ap, *(const float4*)(ap + 4));
#pragma unroll
    for (int nf = 0; nf < 4; ++nf) {
      const float* bp = Wqkv + (size_t)(n0 + nf * 16 + lm) * 256 + k0 + lk;
      short8 b = pk8(*(const float4*)bp, *(const float4*)(bp + 4));
      acc[nf] = __builtin_amdgcn_mfma_f32_16x16x32_bf16(a, b, acc[nf], 0, 0, 0);
    }
  }
  const int rbase = i0 + ((l >> 4) << 2);
#pragma unroll
  for (int nf = 0; nf < 4; ++nf) {
#pragma unroll
    for (int r = 0; r < 4; ++r) {
      int row = rbase + r;
      int c = n0 + nf * 16 + lm;
      int b_ = row >> 9, i = row & 511;
      int h = c / 104, o = c - h * 104;
      float v = acc[nf][r];
      size_t bh = (size_t)(b_ * 8 + h);
      if (o < 32)       Qnb[(bh * 512 + i) * 32 + o] = f2bf(v);
      else if (o < 64)  Knb[(bh * 512 + i) * 32 + (o - 32)] = f2bf(v);
      else if (o < 96)  Vtb[(bh * 32 + (o - 64)) * 512 + i] = f2bf(v);
      else              Qr[(size_t)row * 64 + h * 8 + (o - 96)] = v;
    }
  }
}

// ---------------------------------------------------------------------------
// K1c: qrr[row][h*16+r] = sum_k Qr[row][h*8+k] * Wd[(h*8+k)*16+r]
// ---------------------------------------------------------------------------
__global__ __launch_bounds__(256) void k1c_qrr(const float* __restrict__ Qr,
                                               const float* __restrict__ Wd,
                                               float* __restrict__ qrrg) {
  int t = threadIdx.x;
  int row = blockIdx.x * 2 + (t >> 7);
  int c = t & 127, h = c >> 4, r = c & 15;
  float s = 0.f;
#pragma unroll
  for (int k = 0; k < 8; ++k)
    s += Qr[(size_t)row * 64 + h * 8 + k] * Wd[(h * 8 + k) * 16 + r];
  qrrg[(size_t)row * 128 + c] = s;
}

// ---------------------------------------------------------------------------
// K2: MFMA QK^T per (b,h): sqk[bh][i][j] bf16 = Qn[512,32] @ Kn[512,32]^T
// ---------------------------------------------------------------------------
__global__ __launch_bounds__(256) void k2_qk(const unsigned short* __restrict__ Qnb,
                                             const unsigned short* __restrict__ Knb,
                                             unsigned short* __restrict__ sqk) {
  const int t = threadIdx.x;
  const int w = t >> 6, l = t & 63;
  const int lm = l & 15, lk = (l >> 4) << 3;
  const int bh = blockIdx.z;
  const int i0 = blockIdx.y * 64 + w * 16, j0 = blockIdx.x * 64;
  short8 a = ld8(Qnb + ((size_t)bh * 512 + i0 + lm) * 32 + lk);
  f32x4 acc[4] = {};
#pragma unroll
  for (int nf = 0; nf < 4; ++nf) {
    short8 b = ld8(Knb + ((size_t)bh * 512 + j0 + nf * 16 + lm) * 32 + lk);
    acc[nf] = __builtin_amdgcn_mfma_f32_16x16x32_bf16(a, b, acc[nf], 0, 0, 0);
  }
  const int rbase = i0 + ((l >> 4) << 2);
#pragma unroll
  for (int nf = 0; nf < 4; ++nf)
#pragma unroll
    for (int r = 0; r < 4; ++r)
      sqk[((size_t)bh * 512 + rbase + r) * 512 + j0 + nf * 16 + lm] = f2bf(acc[nf][r]);
}

// ---------------------------------------------------------------------------
// K3: per (b,i): prefetch rd cols + sqk + mask to REGS (issue-early);
//     scores = scale*(sqk + qrr.rd) + mask ; softmax ; probs bf16 -> global;
//     pr[row][h*16+r] = sum_j p*rd -> global (route-ctx folded into k5).
//     rd LDS copy (bf16, stride-9 odd => conflict-free) only serves pass B.
// ---------------------------------------------------------------------------
__global__ __launch_bounds__(256) void k3_route(const float* __restrict__ rd,
                                                const unsigned short* __restrict__ sqk,
                                                const float* __restrict__ qrrg,
                                                const float* __restrict__ mask,
                                                unsigned short* __restrict__ probs,
                                                float* __restrict__ pr) {
  __shared__ unsigned int rdp[512][9];     // bf16 pairs, odd stride
  __shared__ unsigned int sc_bf[8][257];   // packed (j, j+256) bf16 pairs
  __shared__ float qrr[8][16];
  __shared__ float prp[4][64][2];
  __shared__ float prf[8][16];
  const int t = threadIdx.x;
  const int row = blockIdx.x, b = row >> 9, i = row & 511;

  // ---- issue-early: this thread owns j = t (lo) and j = t+256 (hi) ----
  const float4* rbase = (const float4*)(rd + (size_t)row * 8192);
  float4 lo0 = rbase[t * 4 + 0], lo1 = rbase[t * 4 + 1];
  float4 lo2 = rbase[t * 4 + 2], lo3 = rbase[t * 4 + 3];
  float4 hi0 = rbase[(t + 256) * 4 + 0], hi1 = rbase[(t + 256) * 4 + 1];
  float4 hi2 = rbase[(t + 256) * 4 + 2], hi3 = rbase[(t + 256) * 4 + 3];
  const unsigned short* qb = sqk + ((size_t)(b * 8) * 512 + i) * 512;
  unsigned int qk_lo[8], qk_hi[8];
#pragma unroll
  for (int h = 0; h < 8; ++h) {
    qk_lo[h] = qb[(size_t)h * 512 * 512 + t];
    qk_hi[h] = qb[(size_t)h * 512 * 512 + t + 256];
  }
  float mlo = mask[b * 512 + t], mhi = mask[b * 512 + t + 256];
  if (t < 128) ((float*)qrr)[t] = qrrg[(size_t)row * 128 + t];

  // ---- LDS copy for pass B (bf16) ----
  rdp[t][0] = pk2(lo0.x, lo0.y); rdp[t][1] = pk2(lo0.z, lo0.w);
  rdp[t][2] = pk2(lo1.x, lo1.y); rdp[t][3] = pk2(lo1.z, lo1.w);
  rdp[t][4] = pk2(lo2.x, lo2.y); rdp[t][5] = pk2(lo2.z, lo2.w);
  rdp[t][6] = pk2(lo3.x, lo3.y); rdp[t][7] = pk2(lo3.z, lo3.w);
  rdp[t + 256][0] = pk2(hi0.x, hi0.y); rdp[t + 256][1] = pk2(hi0.z, hi0.w);
  rdp[t + 256][2] = pk2(hi1.x, hi1.y); rdp[t + 256][3] = pk2(hi1.z, hi1.w);
  rdp[t + 256][4] = pk2(hi2.x, hi2.y); rdp[t + 256][5] = pk2(hi2.z, hi2.w);
  rdp[t + 256][6] = pk2(hi3.x, hi3.y); rdp[t + 256][7] = pk2(hi3.z, hi3.w);
  __syncthreads();

  // ---- pass A: scores from REG rd (f32, no unpack) ----
  const float scal = 0.15811388300841898f;
#pragma unroll
  for (int h = 0; h < 8; ++h) {
    float slo = qrr[h][0]  * lo0.x + qrr[h][1]  * lo0.y
              + qrr[h][2]  * lo0.z + qrr[h][3]  * lo0.w
              + qrr[h][4]  * lo1.x + qrr[h][5]  * lo1.y
              + qrr[h][6]  * lo1.z + qrr[h][7]  * lo1.w
              + qrr[h][8]  * lo2.x + qrr[h][9]  * lo2.y
              + qrr[h][10] * lo2.z + qrr[h][11] * lo2.w
              + qrr[h][12] * lo3.x + qrr[h][13] * lo3.y
              + qrr[h][14] * lo3.z + qrr[h][15] * lo3.w;
    float shi = qrr[h][0]  * hi0.x + qrr[h][1]  * hi0.y
              + qrr[h][2]  * hi0.z + qrr[h][3]  * hi0.w
              + qrr[h][4]  * hi1.x + qrr[h][5]  * hi1.y
              + qrr[h][6]  * hi1.z + qrr[h][7]  * hi1.w
              + qrr[h][8]  * hi2.x + qrr[h][9]  * hi2.y
              + qrr[h][10] * hi2.z + qrr[h][11] * hi2.w
              + qrr[h][12] * hi3.x + qrr[h][13] * hi3.y
              + qrr[h][14] * hi3.z + qrr[h][15] * hi3.w;
    float vlo = scal * (bfu2f(qk_lo[h]) + slo) + mlo;
    float vhi = scal * (bfu2f(qk_hi[h]) + shi) + mhi;
    sc_bf[h][t] = pk2(vlo, vhi);
  }
  __syncthreads();

  // ---- softmax: wave handles 2 heads ----
  const int wave = t >> 6, lane = t & 63;
  for (int hh = 0; hh < 2; ++hh) {
    int h = wave * 2 + hh;
    float vlo[4], vhi[4];
    float m = -1e30f;
#pragma unroll
    for (int cq = 0; cq < 4; ++cq) {
      unsigned int u = sc_bf[h][lane + 64 * cq];
      vlo[cq] = bfu2f(u & 0xffffu); vhi[cq] = bfu2f(u >> 16);
      m = fmaxf(m, fmaxf(vlo[cq], vhi[cq]));
    }
#pragma unroll
    for (int o = 32; o; o >>= 1) m = fmaxf(m, __shfl_xor(m, o));
    float ssum = 0.f;
#pragma unroll
    for (int cq = 0; cq < 4; ++cq) {
      vlo[cq] = __expf(vlo[cq] - m); vhi[cq] = __expf(vhi[cq] - m);
      ssum += vlo[cq] + vhi[cq];
    }
#pragma unroll
    for (int o = 32; o; o >>= 1) ssum += __shfl_xor(ssum, o);
    float inv = 1.0f / ssum;
    unsigned short* pout = probs + ((size_t)(b * 8 + h) * 512 + i) * 512;
#pragma unroll
    for (int cq = 0; cq < 4; ++cq) {
      int jj = lane + 64 * cq;
      unsigned short plo = f2bf(vlo[cq] * inv), phi = f2bf(vhi[cq] * inv);
      pout[jj] = plo; pout[jj + 256] = phi;
      sc_bf[h][jj] = (unsigned int)plo | ((unsigned int)phi << 16);
    }
  }
  __syncthreads();

  // ---- pass B: pr[h][r] = sum_j p[h][j]*rd[j][r] ----
  {
    int c = t & 63, qj = t >> 6;
    int h = c >> 3, ru = c & 7;
    float p0 = 0.f, p1 = 0.f;
    for (int jj = qj * 64; jj < qj * 64 + 64; ++jj) {
      unsigned int u = sc_bf[h][jj];
      unsigned int rr = rdp[jj][ru];
      unsigned int r2 = rdp[jj + 256][ru];
      float plo = bfu2f(u & 0xffffu), phi = bfu2f(u >> 16);
      p0 += plo * bfu2f(rr & 0xffffu) + phi * bfu2f(r2 & 0xffffu);
      p1 += plo * bfu2f(rr >> 16)     + phi * bfu2f(r2 >> 16);
    }
    prp[qj][c][0] = p0; prp[qj][c][1] = p1;
  }
  __syncthreads();
  if (t < 128) {
    int h = t >> 4, r = t & 15;
    int c = h * 8 + (r >> 1), part = r & 1;
    prf[h][r] = prp[0][c][part] + prp[1][c][part] + prp[2][c][part] + prp[3][c][part];
  }
  __syncthreads();
  if (t < 128) pr[(size_t)row * 128 + t] = prf[t >> 4][t & 15];
}

// ---------------------------------------------------------------------------
// K4: MFMA PV, sole ctx writer (plain stores, no atomics).
// grid (i-tile32 x bh); wave w: i-sub = w&1, v-sub = w>>1.
// ---------------------------------------------------------------------------
__global__ __launch_bounds__(256) void k4_pv(const unsigned short* __restrict__ probs,
                                             const unsigned short* __restrict__ Vtb,
                                             float* __restrict__ ctx) {
  const int t = threadIdx.x;
  const int w = t >> 6, l = t & 63;
  const int lm = l & 15, lk = (l >> 4) << 3;
  const int bh = blockIdx.y;
  const int b = bh >> 3, h = bh & 7;
  const int i0 = blockIdx.x * 32 + (w & 1) * 16;
  const int v0 = (w >> 1) * 16;
  f32x4 acc = {};
  for (int k0 = 0; k0 < 512; k0 += 32) {
    short8 a  = ld8(probs + ((size_t)bh * 512 + i0 + lm) * 512 + k0 + lk);
    short8 bb = ld8(Vtb + ((size_t)bh * 32 + v0 + lm) * 512 + k0 + lk);
    acc = __builtin_amdgcn_mfma_f32_16x16x32_bf16(a, bb, acc, 0, 0, 0);
  }
  const int rbase = i0 + ((l >> 4) << 2);
#pragma unroll
  for (int r = 0; r < 4; ++r)
    ctx[((size_t)b * 512 + rbase + r) * 256 + h * 32 + v0 + lm] = acc[r];
}

// ---------------------------------------------------------------------------
// K5: out = LN(ctx @ Wout^T + pr @ Wco^T + b_out) + H   (4 rows/block)
// ---------------------------------------------------------------------------
__global__ __launch_bounds__(256) void k5_out(const float* __restrict__ ctx,
                                              const float* __restrict__ pr,
                                              const float* __restrict__ Wco,
                                              const float* __restrict__ Wout,
                                              const float* __restrict__ bout,
                                              const float* __restrict__ lnw,
                                              const float* __restrict__ lnb,
                                              const float* __restrict__ Hin,
                                              float* __restrict__ out) {
  __shared__ float buf[4][257];
  __shared__ float prb[4][128];
  __shared__ float uarr[4], rarr[4];
  const int t = threadIdx.x;
  const int R0 = blockIdx.x * 4;
  {
    int sr = t >> 6, c0 = (t & 63) * 4;
    float4 a = *(const float4*)(ctx + (size_t)(R0 + sr) * 256 + c0);
    buf[sr][c0+0]=a.x; buf[sr][c0+1]=a.y; buf[sr][c0+2]=a.z; buf[sr][c0+3]=a.w;
  }
#pragma unroll
  for (int k = 0; k < 2; ++k) {
    int e = k * 256 + t;
    int sr = e >> 7, c = e & 127;
    prb[sr][c] = pr[(size_t)(R0 + sr) * 128 + c];
  }
  __syncthreads();

  float o[4];
  {
    float bo = bout[t];
#pragma unroll
    for (int r = 0; r < 4; ++r) o[r] = bo;
  }
  const float4* wp = (const float4*)(Wout + (size_t)t * 256);
  for (int d4 = 0; d4 < 64; ++d4) {
    float4 w = wp[d4];
    int d = d4 * 4;
#pragma unroll
    for (int r = 0; r < 4; ++r)
      o[r] += buf[r][d]*w.x + buf[r][d+1]*w.y + buf[r][d+2]*w.z + buf[r][d+3]*w.w;
  }
  const float4* wc = (const float4*)(Wco + (size_t)t * 128);
  for (int c4 = 0; c4 < 32; ++c4) {
    float4 w = wc[c4];
    int c = c4 * 4;
#pragma unroll
    for (int r = 0; r < 4; ++r)
      o[r] += prb[r][c]*w.x + prb[r][c+1]*w.y + prb[r][c+2]*w.z + prb[r][c+3]*w.w;
  }
  __syncthreads();
#pragma unroll
  for (int r = 0; r < 4; ++r) buf[r][t] = o[r];
  __syncthreads();
  {
    int wave = t >> 6, lane = t & 63;
    int r = wave;
    float s = 0.f, sq = 0.f;
#pragma unroll
    for (int c = 0; c < 4; ++c) {
      float x = buf[r][lane + 64*c];
      s += x; sq += x*x;
    }
#pragma unroll
    for (int off = 32; off; off >>= 1) {
      s += __shfl_xor(s, off);
      sq += __shfl_xor(sq, off);
    }
    if (lane == 0) {
      float u = s * (1.0f/256.0f);
      uarr[r] = u;
      rarr[r] = rsqrtf(sq * (1.0f/256.0f) - u*u + 1e-12f);
    }
  }
  __syncthreads();
  {
    float lw = lnw[t], lb = lnb[t];
#pragma unroll
    for (int r = 0; r < 4; ++r) {
      size_t R = R0 + r;
      out[R * 256 + t] = lw * (o[r] - uarr[r]) * rarr[r] + lb + Hin[R * 256 + t];
    }
  }
}

// ---------------------------------------------------------------------------
extern "C" void kernel_launch(void* const* d_in, const int* in_sizes, int n_in,
                              void* d_out, int out_size, void* d_ws, size_t ws_size,
                              hipStream_t stream) {
  const float* Hin    = (const float*)d_in[0];
  const float* rd     = (const float*)d_in[1];
  const float* mask   = (const float*)d_in[2];
  const float* Wqkv   = (const float*)d_in[3];
  const float* Wd     = (const float*)d_in[4];
  const float* Wroute = (const float*)d_in[5];
  const float* Wout   = (const float*)d_in[6];
  const float* bout   = (const float*)d_in[7];
  const float* lnw    = (const float*)d_in[8];
  const float* lnb    = (const float*)d_in[9];
  float* out = (float*)d_out;

  unsigned short* Qnb   = (unsigned short*)d_ws;       // 524,288 us
  unsigned short* Knb   = Qnb + 524288;                // 524,288
  unsigned short* Vtb   = Knb + 524288;                // 524,288
  unsigned short* sqk   = Vtb + 524288;                // 8,388,608
  unsigned short* probs = sqk + 8388608;               // 8,388,608
  float* Qr   = (float*)(probs + 8388608);             // 131,072 f
  float* qrrg = Qr + 131072;                           // 262,144 f
  float* ctx  = qrrg + 262144;                         // 524,288 f
  float* prg  = ctx + 524288;                          // 262,144 f
  float* Wco  = prg + 262144;                          //  32,768 f
  // total ~41.6 MB (fits: R1 layout proved >= 42.4 MB available)

  k0_wco  <<<128,            256, 0, stream>>>(Wout, Wroute, Wco);
  k1_qkv  <<<dim3(13, 32),   256, 0, stream>>>(Hin, Wqkv, Qnb, Knb, Vtb, Qr);
  k1c_qrr <<<1024,           256, 0, stream>>>(Qr, Wd, qrrg);
  k2_qk   <<<dim3(8, 8, 32), 256, 0, stream>>>(Qnb, Knb, sqk);
  k3_route<<<2048,           256, 0, stream>>>(rd, sqk, qrrg, mask, probs, prg);
  k4_pv   <<<dim3(16, 32),   256, 0, stream>>>(probs, Vtb, ctx);
  k5_out  <<<512,            256, 0, stream>>>(ctx, prg, Wco, Wout, bout, lnw, lnb, Hin, out);
}